// Round 1
// baseline (634.604 us; speedup 1.0000x reference)
//
#include <hip/hip_runtime.h>
#include <math.h>

namespace {

constexpr int N  = 8192;
constexpr int NT = 256;          // threads per block
constexpr int F4 = N / 4 / NT;   // 8 float4 per thread -> 32 floats
constexpr float EPS = 1e-6f;

__device__ __forceinline__ float waveMax(float v) {
#pragma unroll
  for (int off = 32; off; off >>= 1) v = fmaxf(v, __shfl_xor(v, off, 64));
  return v;
}
__device__ __forceinline__ float waveSum(float v) {
#pragma unroll
  for (int off = 32; off; off >>= 1) v += __shfl_xor(v, off, 64);
  return v;
}
__device__ __forceinline__ unsigned waveSumU(unsigned v) {
#pragma unroll
  for (int off = 32; off; off >>= 1) v += (unsigned)__shfl_xor((int)v, off, 64);
  return v;
}

__global__ void diag_extract(const float* __restrict__ sim, float* __restrict__ dg) {
  int i = blockIdx.x * blockDim.x + threadIdx.x;
  if (i < N) dg[i] = sim[(size_t)i * N + i];
}

__global__ void acc_init(double* acc, unsigned* cnt) {
  acc[0] = 0.0;
  acc[1] = 0.0;
  *cnt = 0u;
}

__launch_bounds__(NT)
__global__ void row_loss(const float* __restrict__ sim,
                         const float* __restrict__ dg,
                         double* __restrict__ acc,
                         unsigned* __restrict__ cnt) {
  __shared__ float shm[4];   // wave maxes
  __shared__ float shs[4];   // wave sums (Z)
  __shared__ float shn[4];   // wave neg sums
  __shared__ float shp[4];   // wave pos terms
  __shared__ unsigned shc[4];// wave counts

  const int row  = blockIdx.x;
  const int t    = threadIdx.x;
  const int wid  = t >> 6;
  const int lane = t & 63;

  const float4* rp = reinterpret_cast<const float4*>(sim + (size_t)row * N);
  const float4* dp = reinterpret_cast<const float4*>(dg);

  // ---- load whole row into registers (coalesced float4) ----
  float x[F4 * 4];
#pragma unroll
  for (int k = 0; k < F4; ++k) {
    float4 v = rp[k * NT + t];
    x[4 * k + 0] = v.x;
    x[4 * k + 1] = v.y;
    x[4 * k + 2] = v.z;
    x[4 * k + 3] = v.w;
  }

  // ---- row max ----
  float lm = -3.4e38f;
#pragma unroll
  for (int i = 0; i < F4 * 4; ++i) lm = fmaxf(lm, x[i]);
  lm = waveMax(lm);
  if (lane == 0) shm[wid] = lm;
  __syncthreads();
  // max(100*x) == 100*max(x) bit-exactly (monotone fp32 scaling)
  const float m = 100.0f * fmaxf(fmaxf(shm[0], shm[1]), fmaxf(shm[2], shm[3]));

  // ---- exp + row sum (keep e in registers) ----
  float e[F4 * 4];
  float ls = 0.0f;
#pragma unroll
  for (int i = 0; i < F4 * 4; ++i) {
    e[i] = __expf(100.0f * x[i] - m);
    ls += e[i];
  }
  ls = waveSum(ls);
  if (lane == 0) shs[wid] = ls;
  __syncthreads();
  const float Z = shs[0] + shs[1] + shs[2] + shs[3];
  const float invZ = 1.0f / Z;
  const float dr = dg[row];

  // ---- per-element terms ----
  float negs = 0.0f;
  float posv = 0.0f;
  unsigned lc = 0;
#pragma unroll
  for (int k = 0; k < F4; ++k) {
    float4 dv = dp[k * NT + t];
#pragma unroll
    for (int c = 0; c < 4; ++c) {
      const int j  = (k * NT + t) * 4 + c;
      const float xi = x[4 * k + c];
      const float dc = (c == 0) ? dv.x : (c == 1) ? dv.y : (c == 2) ? dv.z : dv.w;
      float p  = e[4 * k + c] * invZ;
      float pc = fminf(fmaxf(p, EPS), 1.0f - EPS);
      if (j == row) {
        posv = -__logf(pc);
      } else if (xi > dr || xi > dc) {   // relu(sim-d_i)+relu(sim-d_j) > 0
        ++lc;
        negs += (pc < 1e-3f)
                    ? pc * (1.0f + pc * (0.5f + 0.33333334f * pc))  // -log(1-p) series
                    : -__logf(1.0f - pc);
      }
    }
  }

  negs = waveSum(negs);
  posv = waveSum(posv);
  lc   = waveSumU(lc);
  if (lane == 0) { shn[wid] = negs; shp[wid] = posv; shc[wid] = lc; }
  __syncthreads();
  if (t == 0) {
    float bn = shn[0] + shn[1] + shn[2] + shn[3];
    float bp = shp[0] + shp[1] + shp[2] + shp[3];
    unsigned bc = shc[0] + shc[1] + shc[2] + shc[3];
    atomicAdd(acc, (double)bp);
    atomicAdd(acc + 1, (double)bn);
    atomicAdd(cnt, bc);
  }
}

__global__ void finalize(const double* __restrict__ acc,
                         const unsigned* __restrict__ cnt,
                         float* __restrict__ out) {
  double pos_mean = acc[0] / (double)N;
  unsigned c = *cnt;
  double neg = (c > 0u) ? 0.5 * (acc[1] / (double)c) : 0.0;
  out[0] = (float)(pos_mean + neg);
}

} // namespace

extern "C" void kernel_launch(void* const* d_in, const int* in_sizes, int n_in,
                              void* d_out, int out_size, void* d_ws, size_t ws_size,
                              hipStream_t stream) {
  const float* sim = (const float*)d_in[0];
  float* out = (float*)d_out;

  // workspace layout: [0,16) double acc[2]; [16,20) uint cnt; [64, 64+32KB) diag
  double*   acc = (double*)d_ws;
  unsigned* cnt = (unsigned*)((char*)d_ws + 16);
  float*    dg  = (float*)((char*)d_ws + 64);

  acc_init<<<1, 1, 0, stream>>>(acc, cnt);
  diag_extract<<<N / 256, 256, 0, stream>>>(sim, dg);
  row_loss<<<N, NT, 0, stream>>>(sim, dg, acc, cnt);
  finalize<<<1, 1, 0, stream>>>(acc, cnt, out);
}

// Round 2
// 73.641 us; speedup vs baseline: 8.6175x; 8.6175x over previous
//
#include <hip/hip_runtime.h>
#include <math.h>

namespace {

constexpr int N  = 8192;
constexpr int NT = 256;          // threads per block
constexpr int F4 = N / 4 / NT;   // 8 float4 per thread -> 32 floats
constexpr float EPS = 1e-6f;

__device__ __forceinline__ float waveMax(float v) {
#pragma unroll
  for (int off = 32; off; off >>= 1) v = fmaxf(v, __shfl_xor(v, off, 64));
  return v;
}
__device__ __forceinline__ float waveSum(float v) {
#pragma unroll
  for (int off = 32; off; off >>= 1) v += __shfl_xor(v, off, 64);
  return v;
}
__device__ __forceinline__ unsigned waveSumU(unsigned v) {
#pragma unroll
  for (int off = 32; off; off >>= 1) v += (unsigned)__shfl_xor((int)v, off, 64);
  return v;
}

__global__ void diag_extract(const float* __restrict__ sim, float* __restrict__ dg) {
  int i = blockIdx.x * blockDim.x + threadIdx.x;
  if (i < N) dg[i] = sim[(size_t)i * N + i];
}

__launch_bounds__(NT)
__global__ void row_loss(const float* __restrict__ sim,
                         const float* __restrict__ dg,
                         float* __restrict__ pos_out,
                         float* __restrict__ neg_out,
                         unsigned* __restrict__ cnt_out) {
  __shared__ float shm[4];   // wave maxes
  __shared__ float shs[4];   // wave sums (Z)
  __shared__ float shn[4];   // wave neg sums
  __shared__ float shp[4];   // wave pos terms
  __shared__ unsigned shc[4];// wave counts

  const int row  = blockIdx.x;
  const int t    = threadIdx.x;
  const int wid  = t >> 6;
  const int lane = t & 63;

  const float4* rp = reinterpret_cast<const float4*>(sim + (size_t)row * N);
  const float4* dp = reinterpret_cast<const float4*>(dg);

  // ---- load whole row into registers (coalesced float4) ----
  float x[F4 * 4];
#pragma unroll
  for (int k = 0; k < F4; ++k) {
    float4 v = rp[k * NT + t];
    x[4 * k + 0] = v.x;
    x[4 * k + 1] = v.y;
    x[4 * k + 2] = v.z;
    x[4 * k + 3] = v.w;
  }

  // ---- row max ----
  float lm = -3.4e38f;
#pragma unroll
  for (int i = 0; i < F4 * 4; ++i) lm = fmaxf(lm, x[i]);
  lm = waveMax(lm);
  if (lane == 0) shm[wid] = lm;
  __syncthreads();
  // max(100*x) == 100*max(x) bit-exactly (monotone fp32 scaling)
  const float m = 100.0f * fmaxf(fmaxf(shm[0], shm[1]), fmaxf(shm[2], shm[3]));

  // ---- exp + row sum (keep e in registers) ----
  float e[F4 * 4];
  float ls = 0.0f;
#pragma unroll
  for (int i = 0; i < F4 * 4; ++i) {
    e[i] = __expf(100.0f * x[i] - m);
    ls += e[i];
  }
  ls = waveSum(ls);
  if (lane == 0) shs[wid] = ls;
  __syncthreads();
  const float Z = shs[0] + shs[1] + shs[2] + shs[3];
  const float invZ = 1.0f / Z;
  const float dr = dg[row];

  // ---- per-element terms ----
  float negs = 0.0f;
  float posv = 0.0f;
  unsigned lc = 0;
#pragma unroll
  for (int k = 0; k < F4; ++k) {
    float4 dv = dp[k * NT + t];
#pragma unroll
    for (int c = 0; c < 4; ++c) {
      const int j  = (k * NT + t) * 4 + c;
      const float xi = x[4 * k + c];
      const float dc = (c == 0) ? dv.x : (c == 1) ? dv.y : (c == 2) ? dv.z : dv.w;
      float p  = e[4 * k + c] * invZ;
      float pc = fminf(fmaxf(p, EPS), 1.0f - EPS);
      if (j == row) {
        posv = -__logf(pc);
      } else if (xi > dr || xi > dc) {   // relu(sim-d_i)+relu(sim-d_j) > 0
        ++lc;
        negs += (pc < 1e-3f)
                    ? pc * (1.0f + pc * (0.5f + 0.33333334f * pc))  // -log(1-p) series
                    : -__logf(1.0f - pc);
      }
    }
  }

  negs = waveSum(negs);
  posv = waveSum(posv);
  lc   = waveSumU(lc);
  if (lane == 0) { shn[wid] = negs; shp[wid] = posv; shc[wid] = lc; }
  __syncthreads();
  if (t == 0) {
    // per-row partials -> workspace; NO contended atomics
    pos_out[row] = shp[0] + shp[1] + shp[2] + shp[3];
    neg_out[row] = shn[0] + shn[1] + shn[2] + shn[3];
    cnt_out[row] = shc[0] + shc[1] + shc[2] + shc[3];
  }
}

// single-block final reduction over 8192 per-row partials (96 KB)
__launch_bounds__(NT)
__global__ void reduce_final(const float* __restrict__ pos_in,
                             const float* __restrict__ neg_in,
                             const unsigned* __restrict__ cnt_in,
                             float* __restrict__ out) {
  __shared__ double shp[4], shn[4];
  __shared__ unsigned long long shc[4];

  const int t    = threadIdx.x;
  const int wid  = t >> 6;
  const int lane = t & 63;

  float ps = 0.0f, ns = 0.0f;
  unsigned cs = 0;
  const float4* pp = reinterpret_cast<const float4*>(pos_in);
  const float4* np = reinterpret_cast<const float4*>(neg_in);
  const uint4*  cp = reinterpret_cast<const uint4*>(cnt_in);
#pragma unroll
  for (int k = 0; k < F4; ++k) {
    float4 a = pp[k * NT + t];
    float4 b = np[k * NT + t];
    uint4  c = cp[k * NT + t];
    ps += a.x + a.y + a.z + a.w;
    ns += b.x + b.y + b.z + b.w;
    cs += c.x + c.y + c.z + c.w;
  }
  ps = waveSum(ps);
  ns = waveSum(ns);
  cs = waveSumU(cs);
  if (lane == 0) { shp[wid] = (double)ps; shn[wid] = (double)ns; shc[wid] = (unsigned long long)cs; }
  __syncthreads();
  if (t == 0) {
    double bp = shp[0] + shp[1] + shp[2] + shp[3];
    double bn = shn[0] + shn[1] + shn[2] + shn[3];
    unsigned long long bc = shc[0] + shc[1] + shc[2] + shc[3];
    double pos_mean = bp / (double)N;
    double neg = (bc > 0ull) ? 0.5 * (bn / (double)bc) : 0.0;
    out[0] = (float)(pos_mean + neg);
  }
}

} // namespace

extern "C" void kernel_launch(void* const* d_in, const int* in_sizes, int n_in,
                              void* d_out, int out_size, void* d_ws, size_t ws_size,
                              hipStream_t stream) {
  const float* sim = (const float*)d_in[0];
  float* out = (float*)d_out;

  // workspace layout (all fully rewritten every call):
  // [0,32K)    float pos[8192]
  // [32K,64K)  float neg[8192]
  // [64K,96K)  uint  cnt[8192]
  // [96K,128K) float diag[8192]
  float*    pos = (float*)d_ws;
  float*    neg = (float*)((char*)d_ws + 32 * 1024);
  unsigned* cnt = (unsigned*)((char*)d_ws + 64 * 1024);
  float*    dg  = (float*)((char*)d_ws + 96 * 1024);

  diag_extract<<<N / 256, 256, 0, stream>>>(sim, dg);
  row_loss<<<N, NT, 0, stream>>>(sim, dg, pos, neg, cnt);
  reduce_final<<<1, NT, 0, stream>>>(pos, neg, cnt, out);
}

// Round 3
// 65.767 us; speedup vs baseline: 9.6493x; 1.1197x over previous
//
#include <hip/hip_runtime.h>
#include <math.h>

namespace {

constexpr int N  = 8192;
constexpr int NT = 256;          // threads per block
constexpr int F4 = N / 4 / NT;   // 8 float4 per thread -> 32 floats
constexpr float EPS = 1e-6f;

__device__ __forceinline__ float waveSum(float v) {
#pragma unroll
  for (int off = 32; off; off >>= 1) v += __shfl_xor(v, off, 64);
  return v;
}
__device__ __forceinline__ unsigned waveSumU(unsigned v) {
#pragma unroll
  for (int off = 32; off; off >>= 1) v += (unsigned)__shfl_xor((int)v, off, 64);
  return v;
}

__global__ void diag_extract(const float* __restrict__ sim, float* __restrict__ dg) {
  int i = blockIdx.x * blockDim.x + threadIdx.x;
  if (i < N) dg[i] = sim[(size_t)i * N + i];
}

__launch_bounds__(NT)
__global__ void row_loss(const float* __restrict__ sim,
                         const float* __restrict__ dg,
                         float* __restrict__ pos_out,
                         float* __restrict__ neg_out,
                         unsigned* __restrict__ cnt_out) {
  __shared__ float shm[4];   // per-wave running max
  __shared__ float shs[4];   // per-wave running sum (scaled to shm)
  __shared__ float shn[4];   // per-wave neg sums
  __shared__ float shp[4];   // per-wave pos terms
  __shared__ unsigned shc[4];// per-wave counts

  const int row  = blockIdx.x;
  const int t    = threadIdx.x;
  const int wid  = t >> 6;
  const int lane = t & 63;

  const float4* rp = reinterpret_cast<const float4*>(sim + (size_t)row * N);
  const float4* dp = reinterpret_cast<const float4*>(dg);

  // ---- load whole row into registers (coalesced float4) ----
  float x[F4 * 4];
#pragma unroll
  for (int k = 0; k < F4; ++k) {
    float4 v = rp[k * NT + t];
    x[4 * k + 0] = v.x;
    x[4 * k + 1] = v.y;
    x[4 * k + 2] = v.z;
    x[4 * k + 3] = v.w;
  }

  // ---- per-thread local max, then local scaled sum (no barrier) ----
  float lm = x[0];
#pragma unroll
  for (int i = 1; i < F4 * 4; ++i) lm = fmaxf(lm, x[i]);
  float ls = 0.0f;
#pragma unroll
  for (int i = 0; i < F4 * 4; ++i) ls += __expf(100.0f * (x[i] - lm));

  // ---- wave-level (m,s) combine via shuffles ----
#pragma unroll
  for (int off = 32; off; off >>= 1) {
    float om = __shfl_xor(lm, off, 64);
    float os = __shfl_xor(ls, off, 64);
    float nm = fmaxf(lm, om);
    ls = ls * __expf(100.0f * (lm - nm)) + os * __expf(100.0f * (om - nm));
    lm = nm;
  }
  if (lane == 0) { shm[wid] = lm; shs[wid] = ls; }
  __syncthreads();   // the ONLY block barrier

  // ---- combine 4 wave pairs (every thread, redundantly) ----
  float M = fmaxf(fmaxf(shm[0], shm[1]), fmaxf(shm[2], shm[3]));
  float Z = shs[0] * __expf(100.0f * (shm[0] - M))
          + shs[1] * __expf(100.0f * (shm[1] - M))
          + shs[2] * __expf(100.0f * (shm[2] - M))
          + shs[3] * __expf(100.0f * (shm[3] - M));
  // p_j = exp(100*x_j - C),  C = 100*M + ln Z
  const float C  = fmaf(100.0f, M, __logf(Z));
  const float dr = dg[row];

  // ---- per-element terms (recompute p from x; no e[] array) ----
  float negs = 0.0f;
  float posv = 0.0f;
  unsigned lc = 0;
#pragma unroll
  for (int k = 0; k < F4; ++k) {
    float4 dv = dp[k * NT + t];
#pragma unroll
    for (int c = 0; c < 4; ++c) {
      const int j  = (k * NT + t) * 4 + c;
      const float xi = x[4 * k + c];
      const float dc = (c == 0) ? dv.x : (c == 1) ? dv.y : (c == 2) ? dv.z : dv.w;
      float p  = __expf(fmaf(100.0f, xi, -C));
      float pc = fminf(fmaxf(p, EPS), 1.0f - EPS);
      if (j == row) {
        posv = -__logf(pc);
      } else if (xi > fminf(dr, dc)) {  // relu(x-dr)+relu(x-dc) > 0
        ++lc;
        negs += (pc < 1e-3f)
                    ? pc * (1.0f + pc * (0.5f + 0.33333334f * pc))  // -log(1-p) series
                    : -__logf(1.0f - pc);
      }
    }
  }

  negs = waveSum(negs);
  posv = waveSum(posv);
  lc   = waveSumU(lc);
  if (lane == 0) { shn[wid] = negs; shp[wid] = posv; shc[wid] = lc; }
  __syncthreads();
  if (t == 0) {
    pos_out[row] = shp[0] + shp[1] + shp[2] + shp[3];
    neg_out[row] = shn[0] + shn[1] + shn[2] + shn[3];
    cnt_out[row] = shc[0] + shc[1] + shc[2] + shc[3];
  }
}

// single-block final reduction over 8192 per-row partials (96 KB)
__launch_bounds__(1024)
__global__ void reduce_final(const float* __restrict__ pos_in,
                             const float* __restrict__ neg_in,
                             const unsigned* __restrict__ cnt_in,
                             float* __restrict__ out) {
  __shared__ double shp[16], shn[16];
  __shared__ unsigned long long shc[16];

  const int t    = threadIdx.x;
  const int wid  = t >> 6;
  const int lane = t & 63;

  float ps = 0.0f, ns = 0.0f;
  unsigned cs = 0;
  const float4* pp = reinterpret_cast<const float4*>(pos_in);
  const float4* np = reinterpret_cast<const float4*>(neg_in);
  const uint4*  cp = reinterpret_cast<const uint4*>(cnt_in);
#pragma unroll
  for (int k = 0; k < 2; ++k) {   // 8192/4/1024 = 2
    float4 a = pp[k * 1024 + t];
    float4 b = np[k * 1024 + t];
    uint4  c = cp[k * 1024 + t];
    ps += a.x + a.y + a.z + a.w;
    ns += b.x + b.y + b.z + b.w;
    cs += c.x + c.y + c.z + c.w;
  }
  ps = waveSum(ps);
  ns = waveSum(ns);
  cs = waveSumU(cs);
  if (lane == 0) { shp[wid] = (double)ps; shn[wid] = (double)ns; shc[wid] = (unsigned long long)cs; }
  __syncthreads();
  if (t == 0) {
    double bp = 0.0, bn = 0.0;
    unsigned long long bc = 0;
#pragma unroll
    for (int w = 0; w < 16; ++w) { bp += shp[w]; bn += shn[w]; bc += shc[w]; }
    double pos_mean = bp / (double)N;
    double neg = (bc > 0ull) ? 0.5 * (bn / (double)bc) : 0.0;
    out[0] = (float)(pos_mean + neg);
  }
}

} // namespace

extern "C" void kernel_launch(void* const* d_in, const int* in_sizes, int n_in,
                              void* d_out, int out_size, void* d_ws, size_t ws_size,
                              hipStream_t stream) {
  const float* sim = (const float*)d_in[0];
  float* out = (float*)d_out;

  // workspace layout (all fully rewritten every call):
  // [0,32K)    float pos[8192]
  // [32K,64K)  float neg[8192]
  // [64K,96K)  uint  cnt[8192]
  // [96K,128K) float diag[8192]
  float*    pos = (float*)d_ws;
  float*    neg = (float*)((char*)d_ws + 32 * 1024);
  unsigned* cnt = (unsigned*)((char*)d_ws + 64 * 1024);
  float*    dg  = (float*)((char*)d_ws + 96 * 1024);

  diag_extract<<<N / 256, 256, 0, stream>>>(sim, dg);
  row_loss<<<N, NT, 0, stream>>>(sim, dg, pos, neg, cnt);
  reduce_final<<<1, 1024, 0, stream>>>(pos, neg, cnt, out);
}

// Round 4
// 56.817 us; speedup vs baseline: 11.1693x; 1.1575x over previous
//
#include <hip/hip_runtime.h>
#include <math.h>

namespace {

constexpr int N  = 8192;
constexpr int NT = 256;          // threads per block
constexpr int F4 = N / 4 / NT;   // 8 float4 per thread -> 32 floats
constexpr float EPS = 1e-6f;
constexpr float NLOG_EPS = 13.815511f;   // -ln(1e-6)

__device__ __forceinline__ float waveSum(float v) {
#pragma unroll
  for (int off = 32; off; off >>= 1) v += __shfl_xor(v, off, 64);
  return v;
}
__device__ __forceinline__ unsigned waveSumU(unsigned v) {
#pragma unroll
  for (int off = 32; off; off >>= 1) v += (unsigned)__shfl_xor((int)v, off, 64);
  return v;
}

__global__ void diag_extract(const float* __restrict__ sim, float* __restrict__ dg) {
  int i = blockIdx.x * blockDim.x + threadIdx.x;
  if (i < N) dg[i] = sim[(size_t)i * N + i];
}

__launch_bounds__(NT)
__global__ void row_loss(const float* __restrict__ sim,
                         const float* __restrict__ dg,
                         float* __restrict__ pos_out,
                         float* __restrict__ neg_out,
                         unsigned* __restrict__ cnt_out) {
  __shared__ float shm[4];   // per-wave running max
  __shared__ float shs[4];   // per-wave running sum (scaled to shm)
  __shared__ float shn[4];   // per-wave neg sums
  __shared__ float shp[4];   // per-wave pos terms
  __shared__ unsigned shc[4];// per-wave counts

  const int row  = blockIdx.x;
  const int t    = threadIdx.x;
  const int wid  = t >> 6;
  const int lane = t & 63;

  const float4* rp = reinterpret_cast<const float4*>(sim + (size_t)row * N);
  const float4* dp = reinterpret_cast<const float4*>(dg);

  // ---- load whole row into registers (coalesced float4) ----
  float x[F4 * 4];
#pragma unroll
  for (int k = 0; k < F4; ++k) {
    float4 v = rp[k * NT + t];
    x[4 * k + 0] = v.x;
    x[4 * k + 1] = v.y;
    x[4 * k + 2] = v.z;
    x[4 * k + 3] = v.w;
  }

  // ---- per-thread local max, then local scaled sum (no barrier) ----
  float lm = x[0];
#pragma unroll
  for (int i = 1; i < F4 * 4; ++i) lm = fmaxf(lm, x[i]);
  float ls = 0.0f;
#pragma unroll
  for (int i = 0; i < F4 * 4; ++i) ls += __expf(100.0f * (x[i] - lm));

  // ---- wave-level (m,s) combine via shuffles ----
#pragma unroll
  for (int off = 32; off; off >>= 1) {
    float om = __shfl_xor(lm, off, 64);
    float os = __shfl_xor(ls, off, 64);
    float nm = fmaxf(lm, om);
    ls = ls * __expf(100.0f * (lm - nm)) + os * __expf(100.0f * (om - nm));
    lm = nm;
  }
  if (lane == 0) { shm[wid] = lm; shs[wid] = ls; }
  __syncthreads();   // the ONLY block barrier

  // ---- combine 4 wave pairs (every thread, redundantly) ----
  float M = fmaxf(fmaxf(shm[0], shm[1]), fmaxf(shm[2], shm[3]));
  float Z = shs[0] * __expf(100.0f * (shm[0] - M))
          + shs[1] * __expf(100.0f * (shm[1] - M))
          + shs[2] * __expf(100.0f * (shm[2] - M))
          + shs[3] * __expf(100.0f * (shm[3] - M));
  // p_j = exp(100*x_j - C),  C = 100*M + ln Z
  const float C  = fmaf(100.0f, M, __logf(Z));
  const float dr = dg[row];
  // below xthr, p < EPS -> clipped -> -log(1-p) == EPS exactly (to 5e-13)
  const float xthr = (C - NLOG_EPS) * 0.01f;

  // ---- positive term: diagonal only, once per block ----
  float posv = 0.0f;
  if (t == 0) {
    float pd = __expf(fmaf(100.0f, dr, -C));
    pd = fminf(fmaxf(pd, EPS), 1.0f - EPS);
    posv = -__logf(pd);
  }

  // ---- per-element: selection count + rare exact path ----
  float negs = 0.0f;        // exact terms for near-max elements
  unsigned lc = 0;          // total selected
  unsigned rare = 0;        // selected among near-max (exact-path) elements
#pragma unroll
  for (int k = 0; k < F4; ++k) {
    float4 dv = dp[k * NT + t];
#pragma unroll
    for (int c = 0; c < 4; ++c) {
      const float xi = x[4 * k + c];
      const float dc = (c == 0) ? dv.x : (c == 1) ? dv.y : (c == 2) ? dv.z : dv.w;
      const bool sel = xi > fminf(dr, dc);   // diagonal auto-excluded (x==dr==dc)
      lc += sel ? 1u : 0u;
      if (__builtin_expect(xi > xthr, 0)) {  // ~1-2 lanes per ROW: execz-skipped
        if (sel) {
          float p  = __expf(fmaf(100.0f, xi, -C));
          float pc = fminf(fmaxf(p, EPS), 1.0f - EPS);
          negs += -__logf(1.0f - pc);
          ++rare;
        }
      }
    }
  }
  // all other selected elements contribute exactly EPS each
  negs += EPS * (float)(lc - rare);

  negs = waveSum(negs);
  posv = waveSum(posv);
  lc   = waveSumU(lc);
  if (lane == 0) { shn[wid] = negs; shp[wid] = posv; shc[wid] = lc; }
  __syncthreads();
  if (t == 0) {
    pos_out[row] = shp[0] + shp[1] + shp[2] + shp[3];
    neg_out[row] = shn[0] + shn[1] + shn[2] + shn[3];
    cnt_out[row] = shc[0] + shc[1] + shc[2] + shc[3];
  }
}

// single-block final reduction over 8192 per-row partials (96 KB)
__launch_bounds__(1024)
__global__ void reduce_final(const float* __restrict__ pos_in,
                             const float* __restrict__ neg_in,
                             const unsigned* __restrict__ cnt_in,
                             float* __restrict__ out) {
  __shared__ double shp[16], shn[16];
  __shared__ unsigned long long shc[16];

  const int t    = threadIdx.x;
  const int wid  = t >> 6;
  const int lane = t & 63;

  float ps = 0.0f, ns = 0.0f;
  unsigned cs = 0;
  const float4* pp = reinterpret_cast<const float4*>(pos_in);
  const float4* np = reinterpret_cast<const float4*>(neg_in);
  const uint4*  cp = reinterpret_cast<const uint4*>(cnt_in);
#pragma unroll
  for (int k = 0; k < 2; ++k) {   // 8192/4/1024 = 2
    float4 a = pp[k * 1024 + t];
    float4 b = np[k * 1024 + t];
    uint4  c = cp[k * 1024 + t];
    ps += a.x + a.y + a.z + a.w;
    ns += b.x + b.y + b.z + b.w;
    cs += c.x + c.y + c.z + c.w;
  }
  ps = waveSum(ps);
  ns = waveSum(ns);
  cs = waveSumU(cs);
  if (lane == 0) { shp[wid] = (double)ps; shn[wid] = (double)ns; shc[wid] = (unsigned long long)cs; }
  __syncthreads();
  if (t == 0) {
    double bp = 0.0, bn = 0.0;
    unsigned long long bc = 0;
#pragma unroll
    for (int w = 0; w < 16; ++w) { bp += shp[w]; bn += shn[w]; bc += shc[w]; }
    double pos_mean = bp / (double)N;
    double neg = (bc > 0ull) ? 0.5 * (bn / (double)bc) : 0.0;
    out[0] = (float)(pos_mean + neg);
  }
}

} // namespace

extern "C" void kernel_launch(void* const* d_in, const int* in_sizes, int n_in,
                              void* d_out, int out_size, void* d_ws, size_t ws_size,
                              hipStream_t stream) {
  const float* sim = (const float*)d_in[0];
  float* out = (float*)d_out;

  // workspace layout (all fully rewritten every call):
  // [0,32K)    float pos[8192]
  // [32K,64K)  float neg[8192]
  // [64K,96K)  uint  cnt[8192]
  // [96K,128K) float diag[8192]
  float*    pos = (float*)d_ws;
  float*    neg = (float*)((char*)d_ws + 32 * 1024);
  unsigned* cnt = (unsigned*)((char*)d_ws + 64 * 1024);
  float*    dg  = (float*)((char*)d_ws + 96 * 1024);

  diag_extract<<<N / 256, 256, 0, stream>>>(sim, dg);
  row_loss<<<N, NT, 0, stream>>>(sim, dg, pos, neg, cnt);
  reduce_final<<<1, 1024, 0, stream>>>(pos, neg, cnt, out);
}